// Round 9
// baseline (1169.501 us; speedup 1.0000x reference)
//
#include <hip/hip_runtime.h>

// GCN 3-layer forward on MI355X.
// Pipeline (A_hat (X W) = (A_hat X) W):
//   aggx:  Y1 = A_hat X         GEMM1: H1s = dinv*relu(Y1 W1 + b1)
//   agg256: Y2 = A_hat H1       GEMM2: H2 = relu(Y2 W2 + b2)
//   GEMM3: G3 = dinv*(H2 W3)    aggout: out = dinv[c]*(sum G3[r]+G3[c]) + b3 (f32)
// CSR build: bucketed two-phase fill (round-8 fix for 64B/edge write amplification):
//   k_bucket: count + append packed (r,c) to per-256-node bucket (hot tail lines)
//   k_scan:   offs + dinv
//   k_fill2:  per-bucket block, LDS cursors, contiguous rowidx window writes
// GEMM: m97-style LDS-tiled MFMA (128x128 tile, BK=32, global_load_lds w=16).
// M padded to 100096; padded rows read 0xAA poison (finite), outputs unused.
// Atomics only on memset-initialized arrays; rowidx clamped at read time.

#define IN_F 50
#define HID  256
#define OUT_F 121
#define KP1  64      // layer-1 width padded 50->64
#define NP3  128     // layer-3 N padded 121->128
#define MPAD 100096  // 782 * 128
#define BCAP 6144    // bucket capacity (lambda=4096, +32 sigma)

typedef __attribute__((ext_vector_type(8))) short bf16x8;
typedef __attribute__((ext_vector_type(4))) float f32x4;

__device__ __forceinline__ float bf2f(unsigned short u) {
    union { unsigned int i; float f; } x; x.i = ((unsigned int)u) << 16; return x.f;
}
__device__ __forceinline__ unsigned short f2bf(float f) {
    union { float f; unsigned int i; } x; x.f = f;
    unsigned int r = x.i + 0x7FFFu + ((x.i >> 16) & 1u);  // RNE
    return (unsigned short)(r >> 16);
}

__device__ __forceinline__ void gl2lds16(const void* g, void* l) {
    __builtin_amdgcn_global_load_lds(
        (const __attribute__((address_space(1))) void*)g,
        (__attribute__((address_space(3))) void*)l, 16, 0, 0);
}

// ---- edge dtype detection (int64 vs int32), 64-lane parallel ----------------
__global__ void k_detect(const int* __restrict__ ei, int* __restrict__ flag, int N) {
    int i = threadIdx.x;
    int lo = ei[2 * i], hi = ei[2 * i + 1];
    int bad = (hi != 0) || ((unsigned)lo >= (unsigned)N);
    unsigned long long m = __ballot(bad);
    if (threadIdx.x == 0) *flag = (m == 0ULL) ? 1 : 0;
}

// ---- CSR build (bucketed) ---------------------------------------------------

// count + bucket-append in one edge-list pass
__global__ void k_bucket(const int* __restrict__ ei, const int* __restrict__ flag,
                         int* __restrict__ cnt, int* __restrict__ bcur,
                         int* __restrict__ bbuf, int E, int N) {
    int t = blockIdx.x * blockDim.x + threadIdx.x;
    if (t >= E) return;
    int f = *flag;
    int c = f ? ei[2 * (E + t)] : ei[E + t];
    int r = f ? ei[2 * t] : ei[t];
    c = min(max(c, 0), N - 1);
    r = min(max(r, 0), N - 1);
    atomicAdd(&cnt[c], 1);
    int b = c >> 8;
    int pos = atomicAdd(&bcur[b], 1);
    if (pos < BCAP) bbuf[(size_t)b * BCAP + pos] = (r << 8) | (c & 255);
}

__global__ __launch_bounds__(1024) void k_scan(const int* __restrict__ cnt,
                                               int* __restrict__ offs,
                                               float* __restrict__ dinv, int n) {
    __shared__ int wsum[16];
    __shared__ int s_carry;
    int lane = threadIdx.x & 63, wid = threadIdx.x >> 6;
    if (threadIdx.x == 0) s_carry = 0;
    __syncthreads();
    for (int base = 0; base < n; base += 4096) {
        int i0 = base + (int)threadIdx.x * 4;
        int v0 = (i0 + 0 < n) ? cnt[i0 + 0] : 0;
        int v1 = (i0 + 1 < n) ? cnt[i0 + 1] : 0;
        int v2 = (i0 + 2 < n) ? cnt[i0 + 2] : 0;
        int v3 = (i0 + 3 < n) ? cnt[i0 + 3] : 0;
        int s1 = v0 + v1, s2 = s1 + v2, tsum = s2 + v3;
        int x = tsum;
        #pragma unroll
        for (int d = 1; d < 64; d <<= 1) {
            int y = __shfl_up(x, d, 64);
            if (lane >= d) x += y;
        }
        if (lane == 63) wsum[wid] = x;
        __syncthreads();
        int wpre = 0;
        #pragma unroll
        for (int j = 0; j < 16; j++) wpre += (j < wid) ? wsum[j] : 0;
        int carry = s_carry;
        int e0 = carry + wpre + x - tsum;
        if (i0 + 0 < n) { offs[i0+0]=e0;    dinv[i0+0]=rsqrtf((float)(v0+1)); }
        if (i0 + 1 < n) { offs[i0+1]=e0+v0; dinv[i0+1]=rsqrtf((float)(v1+1)); }
        if (i0 + 2 < n) { offs[i0+2]=e0+s1; dinv[i0+2]=rsqrtf((float)(v2+1)); }
        if (i0 + 3 < n) { offs[i0+3]=e0+s2; dinv[i0+3]=rsqrtf((float)(v3+1)); }
        __syncthreads();
        if (threadIdx.x == 1023) s_carry = carry + wpre + x;
        __syncthreads();
    }
    if (threadIdx.x == 0) offs[n] = s_carry;
}

// one block per bucket: LDS cursors, contiguous rowidx window
__global__ __launch_bounds__(256) void k_fill2(const int* __restrict__ bbuf,
                                               const int* __restrict__ bcur,
                                               const int* __restrict__ offs,
                                               int* __restrict__ rowidx, int E) {
    __shared__ int lcnt[256];
    int b = blockIdx.x;
    lcnt[threadIdx.x] = 0;
    __syncthreads();
    int c0 = b << 8;
    int ne = min(bcur[b], BCAP);
    const int* src = bbuf + (size_t)b * BCAP;
    for (int i = threadIdx.x; i < ne; i += 256) {
        int packed = src[i];
        int local = packed & 255;
        int r = packed >> 8;           // r >= 0, 17 bits — no sign issue
        int pos = offs[c0 + local] + atomicAdd(&lcnt[local], 1);
        if ((unsigned)pos < (unsigned)E) rowidx[pos] = r;
    }
}

// ---- input prep -------------------------------------------------------------

__global__ void k_padx(const float* __restrict__ x, const float* __restrict__ dinv,
                       unsigned short* __restrict__ Xs, int N) {
    int idx = blockIdx.x * blockDim.x + threadIdx.x;
    if (idx >= N * KP1) return;
    int node = idx >> 6, k = idx & 63;
    Xs[idx] = (k < IN_F) ? f2bf(dinv[node] * x[node * IN_F + k]) : (unsigned short)0;
}

__global__ void k_tr(const float* __restrict__ W, unsigned short* __restrict__ Bt,
                     int K, int Nw, int Kp, int Np) {
    int idx = blockIdx.x * blockDim.x + threadIdx.x;
    if (idx >= Np * Kp) return;
    int nn = idx / Kp, k = idx - nn * Kp;
    Bt[idx] = (k < K && nn < Nw) ? f2bf(W[k * Nw + nn]) : (unsigned short)0;
}

// ---- LDS-tiled GEMM (m97 structure) -----------------------------------------
__global__ __launch_bounds__(256) void k_gemm_lds(const unsigned short* __restrict__ A,
                                                  const unsigned short* __restrict__ Bt,
                                                  const float* __restrict__ dinv,
                                                  const float* __restrict__ bias,
                                                  unsigned short* __restrict__ C,
                                                  int K, int Nout,
                                                  int BIAS, int RELU, int SCALE) {
    __shared__ char lds[16384];   // A tile [128][32] bf16 @0, B tile @8192
    const int tid = threadIdx.x;
    const int wid = tid >> 6, lane = tid & 63;
    const int wm = wid & 1, wn = wid >> 1;
    const int quad = lane >> 4, ml = lane & 15;
    const int m0 = blockIdx.x * 128;
    const int n0g = blockIdx.y * 128;

    f32x4 acc[4][4];
    #pragma unroll
    for (int a = 0; a < 4; a++)
        #pragma unroll
        for (int b = 0; b < 4; b++) acc[a][b] = (f32x4){0.f, 0.f, 0.f, 0.f};

    for (int kk = 0; kk < K; kk += 32) {
        #pragma unroll
        for (int r = 0; r < 2; r++) {
            int c = r * 256 + tid;            // chunk 0..511; row=c>>2, quarter=c&3
            int row = c >> 2, q = c & 3;
            gl2lds16(A  + (size_t)(m0  + row) * K + kk + q * 8, lds + c * 16);
            gl2lds16(Bt + (size_t)(n0g + row) * K + kk + q * 8, lds + 8192 + c * 16);
        }
        __syncthreads();
        bf16x8 af[4], bfv[4];
        #pragma unroll
        for (int mf = 0; mf < 4; mf++)
            af[mf] = *(const bf16x8*)(lds + ((wm * 64 + mf * 16 + ml) * 64 + quad * 16));
        #pragma unroll
        for (int nf = 0; nf < 4; nf++)
            bfv[nf] = *(const bf16x8*)(lds + 8192 + ((wn * 64 + nf * 16 + ml) * 64 + quad * 16));
        #pragma unroll
        for (int mf = 0; mf < 4; mf++)
            #pragma unroll
            for (int nf = 0; nf < 4; nf++)
                acc[mf][nf] = __builtin_amdgcn_mfma_f32_16x16x32_bf16(af[mf], bfv[nf], acc[mf][nf], 0, 0, 0);
        __syncthreads();
    }

    #pragma unroll
    for (int mf = 0; mf < 4; mf++) {
        int r0 = m0 + wm * 64 + mf * 16 + quad * 4;
        float dd[4] = {1.f, 1.f, 1.f, 1.f};
        if (SCALE) { dd[0]=dinv[r0]; dd[1]=dinv[r0+1]; dd[2]=dinv[r0+2]; dd[3]=dinv[r0+3]; }
        #pragma unroll
        for (int nf = 0; nf < 4; nf++) {
            int col = n0g + wn * 64 + nf * 16 + ml;
            float bb = BIAS ? bias[col] : 0.f;
            #pragma unroll
            for (int i = 0; i < 4; i++) {
                float v = acc[mf][nf][i] + bb;
                if (RELU) v = fmaxf(v, 0.f);
                v *= dd[i];
                C[(size_t)(r0 + i) * Nout + col] = f2bf(v);
            }
        }
    }
}

// ---- aggregation kernels (gather, unroll-4, read-side index clamp) ----------

__device__ __forceinline__ int rclamp(int r, int N) { return min(max(r, 0), N - 1); }

__global__ void k_aggx(const unsigned short* __restrict__ Xs,
                       const int* __restrict__ offs, const int* __restrict__ rowidx,
                       const float* __restrict__ dinv, unsigned short* __restrict__ Y, int N) {
    int wid = threadIdx.x >> 6, lane = threadIdx.x & 63;
    int node = blockIdx.x * 4 + wid;
    if (node >= N) return;
    float a = bf2f(Xs[(size_t)node * KP1 + lane]);
    int e = offs[node], end = offs[node + 1];
    for (; e + 4 <= end; e += 4) {
        int r0 = rclamp(rowidx[e], N),   r1 = rclamp(rowidx[e+1], N);
        int r2 = rclamp(rowidx[e+2], N), r3 = rclamp(rowidx[e+3], N);
        float g0 = bf2f(Xs[(size_t)r0 * KP1 + lane]);
        float g1 = bf2f(Xs[(size_t)r1 * KP1 + lane]);
        float g2 = bf2f(Xs[(size_t)r2 * KP1 + lane]);
        float g3 = bf2f(Xs[(size_t)r3 * KP1 + lane]);
        a += (g0 + g1) + (g2 + g3);
    }
    for (; e < end; e++) a += bf2f(Xs[(size_t)rclamp(rowidx[e], N) * KP1 + lane]);
    Y[(size_t)node * KP1 + lane] = f2bf(a * dinv[node]);
}

__global__ void k_agg256(const unsigned short* __restrict__ Hn,
                         const int* __restrict__ offs, const int* __restrict__ rowidx,
                         const float* __restrict__ dinv, unsigned short* __restrict__ Y, int N) {
    int wid = threadIdx.x >> 6, lane = threadIdx.x & 63;
    int node = blockIdx.x * 4 + wid;
    if (node >= N) return;
    int c = lane * 4;
    ushort4 s = *(const ushort4*)(Hn + (size_t)node * HID + c);
    float a0 = bf2f(s.x), a1 = bf2f(s.y), a2 = bf2f(s.z), a3 = bf2f(s.w);
    int e = offs[node], end = offs[node + 1];
    for (; e + 4 <= end; e += 4) {
        int r0 = rclamp(rowidx[e], N),   r1 = rclamp(rowidx[e+1], N);
        int r2 = rclamp(rowidx[e+2], N), r3 = rclamp(rowidx[e+3], N);
        ushort4 u0 = *(const ushort4*)(Hn + (size_t)r0 * HID + c);
        ushort4 u1 = *(const ushort4*)(Hn + (size_t)r1 * HID + c);
        ushort4 u2 = *(const ushort4*)(Hn + (size_t)r2 * HID + c);
        ushort4 u3 = *(const ushort4*)(Hn + (size_t)r3 * HID + c);
        a0 += (bf2f(u0.x) + bf2f(u1.x)) + (bf2f(u2.x) + bf2f(u3.x));
        a1 += (bf2f(u0.y) + bf2f(u1.y)) + (bf2f(u2.y) + bf2f(u3.y));
        a2 += (bf2f(u0.z) + bf2f(u1.z)) + (bf2f(u2.z) + bf2f(u3.z));
        a3 += (bf2f(u0.w) + bf2f(u1.w)) + (bf2f(u2.w) + bf2f(u3.w));
    }
    for (; e < end; e++) {
        ushort4 u = *(const ushort4*)(Hn + (size_t)rclamp(rowidx[e], N) * HID + c);
        a0 += bf2f(u.x); a1 += bf2f(u.y); a2 += bf2f(u.z); a3 += bf2f(u.w);
    }
    float dv = dinv[node];
    ushort4 o = make_ushort4(f2bf(a0*dv), f2bf(a1*dv), f2bf(a2*dv), f2bf(a3*dv));
    *(ushort4*)(Y + (size_t)node * HID + c) = o;
}

__global__ void k_aggout(const unsigned short* __restrict__ G,
                         const int* __restrict__ offs, const int* __restrict__ rowidx,
                         const float* __restrict__ dinv, const float* __restrict__ bias,
                         float* __restrict__ out, int N) {
    int wid = threadIdx.x >> 6, lane = threadIdx.x & 63;
    int node = blockIdx.x * 4 + wid;
    if (node >= N) return;
    int c = lane * 2;
    ushort2 s = *(const ushort2*)(G + (size_t)node * NP3 + c);
    float a0 = bf2f(s.x), a1 = bf2f(s.y);
    int e = offs[node], end = offs[node + 1];
    for (; e + 4 <= end; e += 4) {
        int r0 = rclamp(rowidx[e], N),   r1 = rclamp(rowidx[e+1], N);
        int r2 = rclamp(rowidx[e+2], N), r3 = rclamp(rowidx[e+3], N);
        ushort2 u0 = *(const ushort2*)(G + (size_t)r0 * NP3 + c);
        ushort2 u1 = *(const ushort2*)(G + (size_t)r1 * NP3 + c);
        ushort2 u2 = *(const ushort2*)(G + (size_t)r2 * NP3 + c);
        ushort2 u3 = *(const ushort2*)(G + (size_t)r3 * NP3 + c);
        a0 += (bf2f(u0.x) + bf2f(u1.x)) + (bf2f(u2.x) + bf2f(u3.x));
        a1 += (bf2f(u0.y) + bf2f(u1.y)) + (bf2f(u2.y) + bf2f(u3.y));
    }
    for (; e < end; e++) {
        ushort2 u = *(const ushort2*)(G + (size_t)rclamp(rowidx[e], N) * NP3 + c);
        a0 += bf2f(u.x); a1 += bf2f(u.y);
    }
    float dv = dinv[node];
    if (c < OUT_F)     out[(size_t)node * OUT_F + c]     = fmaf(a0, dv, bias[c]);
    if (c + 1 < OUT_F) out[(size_t)node * OUT_F + c + 1] = fmaf(a1, dv, bias[c + 1]);
}

// ---- launch -----------------------------------------------------------------

extern "C" void kernel_launch(void* const* d_in, const int* in_sizes, int n_in,
                              void* d_out, int out_size, void* d_ws, size_t ws_size,
                              hipStream_t stream) {
    const float* x  = (const float*)d_in[0];
    const int*   ei = (const int*)d_in[1];
    const float* W1 = (const float*)d_in[2];
    const float* b1 = (const float*)d_in[3];
    const float* W2 = (const float*)d_in[4];
    const float* b2 = (const float*)d_in[5];
    const float* W3 = (const float*)d_in[6];
    const float* b3 = (const float*)d_in[7];
    float* out = (float*)d_out;

    const int N = in_sizes[0] / IN_F;     // 100000
    const int E = in_sizes[1] / 2;        // 1600000
    const int NB = (N + 255) >> 8;        // 391 buckets

    char* w = (char*)d_ws;
    size_t off = 0;
    auto alloc = [&](size_t bytes) -> char* {
        char* p = w + off;
        off += (bytes + 255) & ~(size_t)255;
        return p;
    };
    int*   cnt    = (int*)  alloc((size_t)N * 4);
    int*   offs   = (int*)  alloc((size_t)(N + 1) * 4);
    int*   bcur   = (int*)  alloc((size_t)NB * 4);
    float* dinv   = (float*)alloc((size_t)MPAD * 4);   // padded: GEMM epilogue reads r<MPAD
    int*   flag   = (int*)  alloc(256);
    int*   rowidx = (int*)  alloc((size_t)E * 4);
    int*   bbuf   = (int*)  alloc((size_t)NB * BCAP * 4);   // 9.6 MB
    unsigned short* Bt1 = (unsigned short*)alloc((size_t)HID * KP1 * 2);
    unsigned short* Bt2 = (unsigned short*)alloc((size_t)HID * HID * 2);
    unsigned short* Bt3 = (unsigned short*)alloc((size_t)NP3 * HID * 2);
    unsigned short* bufA = (unsigned short*)alloc((size_t)MPAD * HID * 2);  // Xs -> H1s -> H2
    unsigned short* bufB = (unsigned short*)alloc((size_t)MPAD * HID * 2);  // Y1 -> Y2 -> G3
    unsigned short* Xs  = bufA;
    unsigned short* Y1  = bufB;
    unsigned short* H1s = bufA;
    unsigned short* Y2  = bufB;
    unsigned short* H2  = bufA;
    unsigned short* G3  = bufB;

    hipMemsetAsync(cnt, 0, (size_t)N * 4, stream);
    hipMemsetAsync(bcur, 0, (size_t)NB * 4, stream);
    hipMemsetAsync(rowidx, 0, (size_t)E * 4, stream);

    k_detect<<<1, 64, 0, stream>>>(ei, flag, N);
    k_bucket<<<(E + 255) / 256, 256, 0, stream>>>(ei, flag, cnt, bcur, bbuf, E, N);
    k_scan<<<1, 1024, 0, stream>>>(cnt, offs, dinv, N);
    k_fill2<<<NB, 256, 0, stream>>>(bbuf, bcur, offs, rowidx, E);

    k_padx<<<(N * KP1 + 255) / 256, 256, 0, stream>>>(x, dinv, Xs, N);
    k_tr<<<(HID * KP1 + 255) / 256, 256, 0, stream>>>(W1, Bt1, IN_F, HID, KP1, HID);
    k_tr<<<(HID * HID + 255) / 256, 256, 0, stream>>>(W2, Bt2, HID, HID, HID, HID);
    k_tr<<<(NP3 * HID + 255) / 256, 256, 0, stream>>>(W3, Bt3, HID, OUT_F, HID, NP3);

    dim3 g12(MPAD / 128, HID / 128);   // (782, 2)
    dim3 g3(MPAD / 128, NP3 / 128);    // (782, 1)
    int aggg = (N + 3) / 4;            // 25000

    // layer 1: aggregate-first, then GEMM (+b1, relu, *dinv)
    k_aggx<<<aggg, 256, 0, stream>>>(Xs, offs, rowidx, dinv, Y1, N);
    k_gemm_lds<<<g12, 256, 0, stream>>>(Y1, Bt1, dinv, b1, H1s, KP1, HID, 1, 1, 1);
    // layer 2: aggregate H1s, then GEMM (+b2, relu)
    k_agg256<<<aggg, 256, 0, stream>>>(H1s, offs, rowidx, dinv, Y2, N);
    k_gemm_lds<<<g12, 256, 0, stream>>>(Y2, Bt2, dinv, b2, H2, HID, HID, 1, 1, 0);
    // layer 3: GEMM (*dinv), then aggregate (+b3), f32 out
    k_gemm_lds<<<g3, 256, 0, stream>>>(H2, Bt3, dinv, b3, G3, HID, NP3, 0, 0, 1);
    k_aggout<<<aggg, 256, 0, stream>>>(G3, offs, rowidx, dinv, b3, out, N);

    (void)n_in; (void)out_size; (void)ws_size;
}